// Round 1
// 1235.049 us; speedup vs baseline: 1.2046x; 1.2046x over previous
//
#include <hip/hip_runtime.h>
#include <hip/hip_bf16.h>

#define VOCAB_SZ 267735
#define NROWS 512

typedef __attribute__((ext_vector_type(8))) short bf16x8;
typedef __attribute__((ext_vector_type(4))) float f32x4;

enum { MODE_Y = 0, MODE_RW = 1 };

// Generic C[512, N] = A[512, K](bf16) @ B[N, K](fp32, converted while staging)^T
// Tile: BM=128, BN=128, BK=32; 256 threads = 4 waves in 2x2; each wave 64x64 via
// 4x4 frags of v_mfma_f32_16x16x32_bf16.
// A-frag: lane holds A[m=lane&15][k=(lane>>4)*8 + j]; B-frag symmetric (n=lane&15).
// C/D: col=lane&15, row=(lane>>4)*4+reg  (learn_hip m89/m91 verified).
//
// MODE_RW: single fused pass — stores raw logit+bias to out (nontemporal),
// accumulates rowsum = sum_n exp(logit+bias), captures pseudo-cluster logits
// (cols Nstore..Nmat) into clog. A later fixup_k adds the per-row/cluster adj.
template<int MODE>
__global__ __launch_bounds__(256)
void gemm_k(const __hip_bfloat16* __restrict__ A, int lda, int Kloop, int K,
            const float* __restrict__ B, const float* __restrict__ B2,
            int Nmat, int Nsplit,
            const float* __restrict__ bias, const float* __restrict__ bias2,
            float* __restrict__ rowsum,
            float* __restrict__ outp, int Nstore,
            float* __restrict__ clog,
            __hip_bfloat16* __restrict__ yout, int yld, int ywidth)
{
    const int t = threadIdx.x;
    const int col0 = blockIdx.x * 128;
    const int row0 = blockIdx.y * 128;
    const int wid = t >> 6, lane = t & 63, q = lane >> 4, l16 = lane & 15;
    const int wm = wid >> 1, wn = wid & 1;

    __shared__ uint4 sA[512];        // 128 rows x 32 bf16 (64B/row)
    __shared__ uint4 sB[512];        // 128 cols x 32 bf16
    __shared__ float rs[2][128];

    f32x4 acc[4][4];
    f32x4 zf = {0.f, 0.f, 0.f, 0.f};
#pragma unroll
    for (int i = 0; i < 4; i++)
#pragma unroll
        for (int j = 0; j < 4; j++) acc[i][j] = zf;

    // staging maps: 2 threads per row/col, 16 k-values each
    const int arow = t >> 1, ahalf = t & 1;
    const __hip_bfloat16* aptr = A + (size_t)(row0 + arow) * lda + ahalf * 16;
    const int bcolg = col0 + (t >> 1);
    const int bkoff = (t & 1) * 16;
    const float* brow = nullptr;
    if (bcolg < Nsplit)      brow = B  + (size_t)bcolg * K;
    else if (bcolg < Nmat)   brow = B2 + (size_t)(bcolg - Nsplit) * K;

    uint4* adst = &sA[(t >> 1) * 4 + (t & 1) * 2];
    uint4* bdst = &sB[(t >> 1) * 4 + (t & 1) * 2];
    const bf16x8* sAv = (const bf16x8*)sA;
    const bf16x8* sBv = (const bf16x8*)sB;

    for (int k0 = 0; k0 < Kloop; k0 += 32) {
        uint4 av0 = ((const uint4*)(aptr + k0))[0];
        uint4 av1 = ((const uint4*)(aptr + k0))[1];
        float4 f0, f1, f2, f3;
        if (brow != nullptr && (k0 + bkoff) < K) {
            const float4* bp = (const float4*)(brow + k0 + bkoff);
            f0 = bp[0]; f1 = bp[1]; f2 = bp[2]; f3 = bp[3];
        } else {
            f0 = make_float4(0.f, 0.f, 0.f, 0.f);
            f1 = f0; f2 = f0; f3 = f0;
        }
        __hip_bfloat16 hb[16] __attribute__((aligned(16)));
        hb[0]  = __float2bfloat16(f0.x); hb[1]  = __float2bfloat16(f0.y);
        hb[2]  = __float2bfloat16(f0.z); hb[3]  = __float2bfloat16(f0.w);
        hb[4]  = __float2bfloat16(f1.x); hb[5]  = __float2bfloat16(f1.y);
        hb[6]  = __float2bfloat16(f1.z); hb[7]  = __float2bfloat16(f1.w);
        hb[8]  = __float2bfloat16(f2.x); hb[9]  = __float2bfloat16(f2.y);
        hb[10] = __float2bfloat16(f2.z); hb[11] = __float2bfloat16(f2.w);
        hb[12] = __float2bfloat16(f3.x); hb[13] = __float2bfloat16(f3.y);
        hb[14] = __float2bfloat16(f3.z); hb[15] = __float2bfloat16(f3.w);

        __syncthreads();
        adst[0] = av0; adst[1] = av1;
        bdst[0] = ((uint4*)hb)[0]; bdst[1] = ((uint4*)hb)[1];
        __syncthreads();

        bf16x8 af[4], bfr[4];
#pragma unroll
        for (int i = 0; i < 4; i++) af[i]  = sAv[(wm * 64 + i * 16 + l16) * 4 + q];
#pragma unroll
        for (int j = 0; j < 4; j++) bfr[j] = sBv[(wn * 64 + j * 16 + l16) * 4 + q];
#pragma unroll
        for (int i = 0; i < 4; i++)
#pragma unroll
            for (int j = 0; j < 4; j++)
                acc[i][j] = __builtin_amdgcn_mfma_f32_16x16x32_bf16(af[i], bfr[j], acc[i][j], 0, 0, 0);
    }

    int colg[4];
#pragma unroll
    for (int j = 0; j < 4; j++) colg[j] = col0 + wn * 64 + j * 16 + l16;

    if (MODE == MODE_Y) {
#pragma unroll
        for (int i = 0; i < 4; i++) {
            int rbase = row0 + wm * 64 + i * 16 + q * 4;
#pragma unroll
            for (int j = 0; j < 4; j++) {
                if (colg[j] < ywidth) {
#pragma unroll
                    for (int r = 0; r < 4; r++)
                        yout[(size_t)(rbase + r) * yld + colg[j]] = __float2bfloat16(acc[i][j][r]);
                }
            }
        }
    } else { // MODE_RW: store raw logits + rowsum reduce + cluster-logit capture
        float bv[4]; bool ok[4];
#pragma unroll
        for (int j = 0; j < 4; j++) {
            ok[j] = colg[j] < Nmat;
            bv[j] = colg[j] < Nsplit ? bias[colg[j]] : (ok[j] ? bias2[colg[j] - Nsplit] : 0.f);
        }
#pragma unroll
        for (int i = 0; i < 4; i++) {
            int rbase = row0 + wm * 64 + i * 16 + q * 4;
#pragma unroll
            for (int r = 0; r < 4; r++) {
                int rg = rbase + r;
                float* orow = outp + (size_t)rg * VOCAB_SZ;
                float s = 0.f;
#pragma unroll
                for (int j = 0; j < 4; j++) {
                    if (ok[j]) {
                        float v = acc[i][j][r] + bv[j];
                        s += __expf(v);
                        if (colg[j] < Nstore)
                            __builtin_nontemporal_store(v, orow + colg[j]);
                        else if (clog != nullptr)
                            clog[(colg[j] - Nstore) * NROWS + rg] = v;
                    }
                }
                s += __shfl_xor(s, 1);
                s += __shfl_xor(s, 2);
                s += __shfl_xor(s, 4);
                s += __shfl_xor(s, 8);
                if (l16 == 0) rs[wn][wm * 64 + i * 16 + q * 4 + r] = s;
            }
        }
        __syncthreads();
        if (t < 128) atomicAdd(&rowsum[row0 + t], rs[0][t] + rs[1][t]);
    }
}

__global__ void prep_k(const float* __restrict__ h, __hip_bfloat16* __restrict__ hb,
                       float* __restrict__ rowsum)
{
    int gid = blockIdx.x * 256 + threadIdx.x;
    if (gid < NROWS * 1024) hb[gid] = __float2bfloat16(h[gid]);
    if (gid < 2048) rowsum[gid] = 0.f;
}

__global__ void finalize_k(const float* __restrict__ rowsum, const float* __restrict__ clog,
                           float* __restrict__ adj)
{
    int r = threadIdx.x; // 512 threads, 1 block
    float lse0 = logf(rowsum[r]);
    adj[r]        = -lse0;
    adj[512 + r]  = clog[r]        - lse0 - logf(rowsum[512 + r]);
    adj[1024 + r] = clog[512 + r]  - lse0 - logf(rowsum[1024 + r]);
    adj[1536 + r] = clog[1024 + r] - lse0 - logf(rowsum[1536 + r]);
}

// out[r][c] += adj[cluster(c)][r]   (548 MB read + 548 MB write, BW-bound)
__global__ __launch_bounds__(256)
void fixup_k(float* __restrict__ out, const float* __restrict__ adj)
{
    const int r = blockIdx.y;
    const float a0 = adj[r], a1 = adj[512 + r], a2 = adj[1024 + r], a3 = adj[1536 + r];
    float* row = out + (size_t)r * VOCAB_SZ;
    // row base alignment: VOCAB_SZ % 4 == 3, so rows are not all 16B-aligned
    const int lead = (int)((4u - ((((size_t)row) >> 2) & 3u)) & 3u);
    const int tid = blockIdx.x * 256 + threadIdx.x;
    const int nth = gridDim.x * 256;
    if (blockIdx.x == 0 && threadIdx.x < lead)
        row[threadIdx.x] += a0;                        // lead cols are < 20000 (cluster 0)
    const int nvec = (VOCAB_SZ - lead) >> 2;
    f32x4* vrow = (f32x4*)(row + lead);
    for (int v = tid; v < nvec; v += nth) {
        const int c = lead + (v << 2);
        f32x4 x = __builtin_nontemporal_load(vrow + v);
        x[0] += (c     < 20000) ? a0 : (c     < 40000) ? a1 : (c     < 200000) ? a2 : a3;
        x[1] += (c + 1 < 20000) ? a0 : (c + 1 < 40000) ? a1 : (c + 1 < 200000) ? a2 : a3;
        x[2] += (c + 2 < 20000) ? a0 : (c + 2 < 40000) ? a1 : (c + 2 < 200000) ? a2 : a3;
        x[3] += (c + 3 < 20000) ? a0 : (c + 3 < 40000) ? a1 : (c + 3 < 200000) ? a2 : a3;
        __builtin_nontemporal_store(x, vrow + v);
    }
    for (int c = lead + (nvec << 2) + tid; c < VOCAB_SZ; c += nth)
        row[c] += a3;                                  // tail cols are >= 200000 (cluster 3)
}

__global__ void loss_k(const float* __restrict__ out, const int* __restrict__ tgt,
                       float* __restrict__ lossp)
{
    __shared__ float sm[512];
    int t = threadIdx.x;
    sm[t] = out[(size_t)t * VOCAB_SZ + tgt[t]];
    __syncthreads();
    for (int s = 256; s > 0; s >>= 1) {
        if (t < s) sm[t] += sm[t + s];
        __syncthreads();
    }
    if (t == 0) lossp[0] = -sm[0] / 512.f;
}

extern "C" void kernel_launch(void* const* d_in, const int* in_sizes, int n_in,
                              void* d_out, int out_size, void* d_ws, size_t ws_size,
                              hipStream_t stream)
{
    const float* hidden = (const float*)d_in[0];
    const int*   target = (const int*)d_in[1];
    const float* cw     = (const float*)d_in[2];
    const float* cb     = (const float*)d_in[3];
    const float* proj[4] = {(const float*)d_in[4], (const float*)d_in[7],
                            (const float*)d_in[10], (const float*)d_in[13]};
    const float* W[4]    = {(const float*)d_in[5], (const float*)d_in[8],
                            (const float*)d_in[11], (const float*)d_in[14]};
    const float* bb[4]   = {(const float*)d_in[6], (const float*)d_in[9],
                            (const float*)d_in[12], (const float*)d_in[15]};
    float* out = (float*)d_out;

    char* ws = (char*)d_ws;
    __hip_bfloat16* hb = (__hip_bfloat16*)ws;                     // 512x1024 bf16
    __hip_bfloat16* y0 = (__hip_bfloat16*)(ws + 1048576);         // 512x1024
    __hip_bfloat16* y1 = (__hip_bfloat16*)(ws + 2097152);         // 512x256
    __hip_bfloat16* y2 = (__hip_bfloat16*)(ws + 2359296);         // 512x64
    __hip_bfloat16* y3 = (__hip_bfloat16*)(ws + 2424832);         // 512x32 (K=16 zero-padded)
    float* rowsum = (float*)(ws + 2490368);                       // [4][512]
    float* adj    = (float*)(ws + 2498560);                       // [4][512]
    float* clog   = (float*)(ws + 2506752);                       // [3][512]

    prep_k<<<2048, 256, 0, stream>>>(hidden, hb, rowsum);

    // y_i = hidden @ proj_i^T  (bf16 out)
    gemm_k<MODE_Y><<<dim3(8, 4), 256, 0, stream>>>(hb, 1024, 1024, 1024, proj[0], proj[0],
        1024, 1024, nullptr, nullptr, nullptr, nullptr, 0, nullptr, y0, 1024, 1024);
    gemm_k<MODE_Y><<<dim3(2, 4), 256, 0, stream>>>(hb, 1024, 1024, 1024, proj[1], proj[1],
        256, 256, nullptr, nullptr, nullptr, nullptr, 0, nullptr, y1, 256, 256);
    gemm_k<MODE_Y><<<dim3(1, 4), 256, 0, stream>>>(hb, 1024, 1024, 1024, proj[2], proj[2],
        64, 64, nullptr, nullptr, nullptr, nullptr, 0, nullptr, y2, 64, 64);
    gemm_k<MODE_Y><<<dim3(1, 4), 256, 0, stream>>>(hb, 1024, 1024, 1024, proj[3], proj[3],
        16, 16, nullptr, nullptr, nullptr, nullptr, 0, nullptr, y3, 32, 32);

    // single fused pass: raw logits -> out, rowsums, cluster-logit capture
    gemm_k<MODE_RW><<<dim3(157, 4), 256, 0, stream>>>(y0, 1024, 1024, 1024, W[0], cw,
        20003, 20000, bb[0], cb, rowsum, out, 20000, clog, nullptr, 0, 0);
    gemm_k<MODE_RW><<<dim3(157, 4), 256, 0, stream>>>(y1, 256, 256, 256, W[1], W[1],
        20000, 20000, bb[1], bb[1], rowsum + 512, out + 20000, 20000, nullptr, nullptr, 0, 0);
    gemm_k<MODE_RW><<<dim3(1250, 4), 256, 0, stream>>>(y2, 64, 64, 64, W[2], W[2],
        160000, 160000, bb[2], bb[2], rowsum + 1024, out + 40000, 160000, nullptr, nullptr, 0, 0);
    gemm_k<MODE_RW><<<dim3(530, 4), 256, 0, stream>>>(y3, 32, 32, 16, W[3], W[3],
        67735, 67735, bb[3], bb[3], rowsum + 1536, out + 200000, 67735, nullptr, nullptr, 0, 0);

    finalize_k<<<1, 512, 0, stream>>>(rowsum, clog, adj);

    // out += adj[cluster][row]  (in-place, memory-bound)
    fixup_k<<<dim3(32, 512), 256, 0, stream>>>(out, adj);

    loss_k<<<1, 512, 0, stream>>>(out, target, out + (out_size - 1));
}

// Round 2
// 1126.631 us; speedup vs baseline: 1.3206x; 1.0962x over previous
//
#include <hip/hip_runtime.h>
#include <hip/hip_bf16.h>

#define VOCAB_SZ 267735
#define NROWS 512

typedef __attribute__((ext_vector_type(8))) short bf16x8;
typedef __attribute__((ext_vector_type(4))) float f32x4;

typedef const __attribute__((address_space(1))) unsigned int* gas_u32p;
typedef __attribute__((address_space(3))) unsigned int* las_u32p;

// 16B async global->LDS DMA (gfx950). LDS dest must be linear: base + lane*16.
#define GLOAD_LDS16(g, l) \
    __builtin_amdgcn_global_load_lds((gas_u32p)(const void*)(g), (las_u32p)(void*)(l), 16, 0, 0)

enum { MODE_Y = 0, MODE_RW = 1 };

// C[512, N] = A[512, K](bf16) @ B[Npad, K](bf16)^T.  All staging via
// global_load_lds width=16 (no VALU conversion, no VGPR round trip).
// Tile: BM=128, BN=128, BK=32; 256 threads = 4 waves in 2x2; each wave 64x64 via
// 4x4 frags of v_mfma_f32_16x16x32_bf16.
// B is pre-padded to Npad (x128) rows so staging never goes OOB; epilogue guards
// with Nmat/Nstore.  C/D: col=lane&15, row=(lane>>4)*4+reg (m89/m91 verified).
template<int MODE>
__global__ __launch_bounds__(256)
void gemm_k(const __hip_bfloat16* __restrict__ A, int lda, int K,
            const __hip_bfloat16* __restrict__ B,
            int Nmat, int Nsplit,
            const float* __restrict__ bias, const float* __restrict__ bias2,
            float* __restrict__ rowsum,
            float* __restrict__ outp, int Nstore,
            float* __restrict__ clog,
            __hip_bfloat16* __restrict__ yout, int yld, int ywidth)
{
    const int t = threadIdx.x;
    const int col0 = blockIdx.x * 128;
    const int row0 = blockIdx.y * 128;
    const int wid = t >> 6, lane = t & 63, q = lane >> 4, l16 = lane & 15;
    const int wm = wid >> 1, wn = wid & 1;

    __shared__ __hip_bfloat16 sA[128 * 32];   // row-major, 64 B/row
    __shared__ __hip_bfloat16 sB[128 * 32];
    __shared__ float rs[2][128];

    f32x4 acc[4][4];
    f32x4 zf = {0.f, 0.f, 0.f, 0.f};
#pragma unroll
    for (int i = 0; i < 4; i++)
#pragma unroll
        for (int j = 0; j < 4; j++) acc[i][j] = zf;

    // staging map: 512 chunks of 16B per tile; chunk id -> (row = id>>2, k-half = (id&3)*8)
    const int id0 = t, id1 = 256 + t;
    const __hip_bfloat16* a0 = A + (size_t)(row0 + (id0 >> 2)) * lda + ((id0 & 3) << 3);
    const __hip_bfloat16* a1 = A + (size_t)(row0 + (id1 >> 2)) * lda + ((id1 & 3) << 3);
    const __hip_bfloat16* b0 = B + (size_t)(col0 + (id0 >> 2)) * K + ((id0 & 3) << 3);
    const __hip_bfloat16* b1 = B + (size_t)(col0 + (id1 >> 2)) * K + ((id1 & 3) << 3);
    char* sAb = (char*)sA;
    char* sBb = (char*)sB;
    const bf16x8* sAv = (const bf16x8*)sA;
    const bf16x8* sBv = (const bf16x8*)sB;

    for (int k0 = 0; k0 < K; k0 += 32) {
        __syncthreads();                       // prev iter's ds_reads drained
        GLOAD_LDS16(a0 + k0, sAb + id0 * 16);
        GLOAD_LDS16(a1 + k0, sAb + id1 * 16);
        GLOAD_LDS16(b0 + k0, sBb + id0 * 16);
        GLOAD_LDS16(b1 + k0, sBb + id1 * 16);
        __syncthreads();                       // vmcnt(0) drain: DMA data visible

        bf16x8 af[4], bfr[4];
#pragma unroll
        for (int i = 0; i < 4; i++) af[i]  = sAv[(wm * 64 + i * 16 + l16) * 4 + q];
#pragma unroll
        for (int j = 0; j < 4; j++) bfr[j] = sBv[(wn * 64 + j * 16 + l16) * 4 + q];
#pragma unroll
        for (int i = 0; i < 4; i++)
#pragma unroll
            for (int j = 0; j < 4; j++)
                acc[i][j] = __builtin_amdgcn_mfma_f32_16x16x32_bf16(af[i], bfr[j], acc[i][j], 0, 0, 0);
    }

    int colg[4];
#pragma unroll
    for (int j = 0; j < 4; j++) colg[j] = col0 + wn * 64 + j * 16 + l16;

    if (MODE == MODE_Y) {
#pragma unroll
        for (int i = 0; i < 4; i++) {
            int rbase = row0 + wm * 64 + i * 16 + q * 4;
#pragma unroll
            for (int j = 0; j < 4; j++) {
                if (colg[j] < ywidth) {
#pragma unroll
                    for (int r = 0; r < 4; r++)
                        yout[(size_t)(rbase + r) * yld + colg[j]] = __float2bfloat16(acc[i][j][r]);
                }
            }
        }
    } else { // MODE_RW: store raw logits + rowsum reduce + cluster-logit capture
        float bv[4]; bool ok[4];
#pragma unroll
        for (int j = 0; j < 4; j++) {
            ok[j] = colg[j] < Nmat;
            bv[j] = colg[j] < Nsplit ? bias[colg[j]] : (ok[j] ? bias2[colg[j] - Nsplit] : 0.f);
        }
#pragma unroll
        for (int i = 0; i < 4; i++) {
            int rbase = row0 + wm * 64 + i * 16 + q * 4;
#pragma unroll
            for (int r = 0; r < 4; r++) {
                int rg = rbase + r;
                float* orow = outp + (size_t)rg * VOCAB_SZ;
                float s = 0.f;
#pragma unroll
                for (int j = 0; j < 4; j++) {
                    if (ok[j]) {
                        float v = acc[i][j][r] + bv[j];
                        s += __expf(v);
                        if (colg[j] < Nstore)
                            __builtin_nontemporal_store(v, orow + colg[j]);
                        else if (clog != nullptr)
                            clog[(colg[j] - Nstore) * NROWS + rg] = v;
                    }
                }
                s += __shfl_xor(s, 1);
                s += __shfl_xor(s, 2);
                s += __shfl_xor(s, 4);
                s += __shfl_xor(s, 8);
                if (l16 == 0) rs[wn][wm * 64 + i * 16 + q * 4 + r] = s;
            }
        }
        __syncthreads();
        if (t < 128) atomicAdd(&rowsum[row0 + t], rs[0][t] + rs[1][t]);
    }
}

// ---- one-shot fp32 -> bf16 weight conversion / layout pass -------------------
__device__ inline void cvt8_store(__hip_bfloat16* dst, const float* src)
{
    float4 f0 = ((const float4*)src)[0];
    float4 f1 = ((const float4*)src)[1];
    __hip_bfloat16 h[8] __attribute__((aligned(16)));
    h[0] = __float2bfloat16(f0.x); h[1] = __float2bfloat16(f0.y);
    h[2] = __float2bfloat16(f0.z); h[3] = __float2bfloat16(f0.w);
    h[4] = __float2bfloat16(f1.x); h[5] = __float2bfloat16(f1.y);
    h[6] = __float2bfloat16(f1.z); h[7] = __float2bfloat16(f1.w);
    *((uint4*)dst) = *((uint4*)h);
}
__device__ inline void zero8_store(__hip_bfloat16* dst)
{
    uint4 z = {0u, 0u, 0u, 0u};
    *((uint4*)dst) = z;
}

// Builds (all bf16): hb[512][1024]; pj[1408][1024] = proj0|proj1|proj2|proj3|0;
// wb0[20096][1024] = W0|cw|0; wb1[20096][256] = W1|0; wb2[160000][64] = W2;
// wb3[67840][32] = W3 (K 16->32 zero-padded)|0.  Also zeroes rowsum.
// Chunk = 8 dst elements.
__global__ __launch_bounds__(256)
void conv_k(const float* __restrict__ hidden, const float* __restrict__ cw,
            const float* __restrict__ p0, const float* __restrict__ p1,
            const float* __restrict__ p2, const float* __restrict__ p3,
            const float* __restrict__ W0, const float* __restrict__ W1,
            const float* __restrict__ W2, const float* __restrict__ W3,
            __hip_bfloat16* __restrict__ hb, __hip_bfloat16* __restrict__ pj,
            __hip_bfloat16* __restrict__ wb0, __hip_bfloat16* __restrict__ wb1,
            __hip_bfloat16* __restrict__ wb2, __hip_bfloat16* __restrict__ wb3,
            float* __restrict__ rowsum)
{
    const long gid0 = (long)blockIdx.x * 256 + threadIdx.x;
    if (gid0 < 512) ((float4*)rowsum)[gid0] = make_float4(0.f, 0.f, 0.f, 0.f);
    const long stride = (long)gridDim.x * 256;
    for (long c = gid0; c < 5012480L; c += stride) {
        if (c < 65536L)        { long o = c * 8;              cvt8_store(hb + o, hidden + o); }
        else if (c < 196608L)  { long o = (c - 65536L) * 8;   cvt8_store(pj + o, p0 + o); }
        else if (c < 229376L)  { long o = (c - 196608L) * 8;  cvt8_store(pj + 1048576L + o, p1 + o); }
        else if (c < 237568L)  { long o = (c - 229376L) * 8;  cvt8_store(pj + 1310720L + o, p2 + o); }
        else if (c < 239616L)  { long o = (c - 237568L) * 8;  cvt8_store(pj + 1376256L + o, p3 + o); }
        else if (c < 245760L)  { long o = (c - 239616L) * 8;  zero8_store(pj + 1392640L + o); }
        else if (c < 2805760L) { long o = (c - 245760L) * 8;  cvt8_store(wb0 + o, W0 + o); }
        else if (c < 2806144L) { long o = (c - 2805760L) * 8; cvt8_store(wb0 + 20480000L + o, cw + o); }
        else if (c < 2818048L) { long o = (c - 2806144L) * 8; zero8_store(wb0 + 20483072L + o); }
        else if (c < 3458048L) { long o = (c - 2818048L) * 8; cvt8_store(wb1 + o, W1 + o); }
        else if (c < 3461120L) { long o = (c - 3458048L) * 8; zero8_store(wb1 + 5120000L + o); }
        else if (c < 4741120L) { long o = (c - 3461120L) * 8; cvt8_store(wb2 + o, W2 + o); }
        else {
            long o = (c - 4741120L) * 8;
            long row = o >> 5; int col = (int)(o & 31);
            if (row < 67735L && col < 16) cvt8_store(wb3 + o, W3 + row * 16 + col);
            else                          zero8_store(wb3 + o);
        }
    }
}

__global__ void finalize_k(const float* __restrict__ rowsum, const float* __restrict__ clog,
                           float* __restrict__ adj)
{
    int r = threadIdx.x; // 512 threads, 1 block
    float lse0 = logf(rowsum[r]);
    adj[r]        = -lse0;
    adj[512 + r]  = clog[r]        - lse0 - logf(rowsum[512 + r]);
    adj[1024 + r] = clog[512 + r]  - lse0 - logf(rowsum[1024 + r]);
    adj[1536 + r] = clog[1024 + r] - lse0 - logf(rowsum[1536 + r]);
}

// out[r][c] += adj[cluster(c)][r]   (548 MB read + 548 MB write, BW-bound)
__global__ __launch_bounds__(256)
void fixup_k(float* __restrict__ out, const float* __restrict__ adj)
{
    const int r = blockIdx.y;
    const float a0 = adj[r], a1 = adj[512 + r], a2 = adj[1024 + r], a3 = adj[1536 + r];
    float* row = out + (size_t)r * VOCAB_SZ;
    // row base alignment: VOCAB_SZ % 4 == 3, so rows are not all 16B-aligned
    const int lead = (int)((4u - ((((size_t)row) >> 2) & 3u)) & 3u);
    const int tid = blockIdx.x * 256 + threadIdx.x;
    const int nth = gridDim.x * 256;
    if (blockIdx.x == 0 && threadIdx.x < lead)
        row[threadIdx.x] += a0;                        // lead cols are < 20000 (cluster 0)
    const int nvec = (VOCAB_SZ - lead) >> 2;
    f32x4* vrow = (f32x4*)(row + lead);
    for (int v = tid; v < nvec; v += nth) {
        const int c = lead + (v << 2);
        f32x4 x = __builtin_nontemporal_load(vrow + v);
        x[0] += (c     < 20000) ? a0 : (c     < 40000) ? a1 : (c     < 200000) ? a2 : a3;
        x[1] += (c + 1 < 20000) ? a0 : (c + 1 < 40000) ? a1 : (c + 1 < 200000) ? a2 : a3;
        x[2] += (c + 2 < 20000) ? a0 : (c + 2 < 40000) ? a1 : (c + 2 < 200000) ? a2 : a3;
        x[3] += (c + 3 < 20000) ? a0 : (c + 3 < 40000) ? a1 : (c + 3 < 200000) ? a2 : a3;
        __builtin_nontemporal_store(x, vrow + v);
    }
    for (int c = lead + (nvec << 2) + tid; c < VOCAB_SZ; c += nth)
        row[c] += a3;                                  // tail cols are >= 200000 (cluster 3)
}

__global__ void loss_k(const float* __restrict__ out, const int* __restrict__ tgt,
                       float* __restrict__ lossp)
{
    __shared__ float sm[512];
    int t = threadIdx.x;
    sm[t] = out[(size_t)t * VOCAB_SZ + tgt[t]];
    __syncthreads();
    for (int s = 256; s > 0; s >>= 1) {
        if (t < s) sm[t] += sm[t + s];
        __syncthreads();
    }
    if (t == 0) lossp[0] = -sm[0] / 512.f;
}

extern "C" void kernel_launch(void* const* d_in, const int* in_sizes, int n_in,
                              void* d_out, int out_size, void* d_ws, size_t ws_size,
                              hipStream_t stream)
{
    const float* hidden = (const float*)d_in[0];
    const int*   target = (const int*)d_in[1];
    const float* cw     = (const float*)d_in[2];
    const float* cb     = (const float*)d_in[3];
    const float* proj[4] = {(const float*)d_in[4], (const float*)d_in[7],
                            (const float*)d_in[10], (const float*)d_in[13]};
    const float* W[4]    = {(const float*)d_in[5], (const float*)d_in[8],
                            (const float*)d_in[11], (const float*)d_in[14]};
    const float* bb[4]   = {(const float*)d_in[6], (const float*)d_in[9],
                            (const float*)d_in[12], (const float*)d_in[15]};
    float* out = (float*)d_out;

    char* ws = (char*)d_ws;
    __hip_bfloat16* hb  = (__hip_bfloat16*)ws;                    // 512x1024
    __hip_bfloat16* y   = (__hip_bfloat16*)(ws + 1048576);        // 512x1408 (y0|y1|y2|y3|0)
    __hip_bfloat16* pj  = (__hip_bfloat16*)(ws + 2490368);        // 1408x1024
    __hip_bfloat16* wb0 = (__hip_bfloat16*)(ws + 5373952);        // 20096x1024
    __hip_bfloat16* wb1 = (__hip_bfloat16*)(ws + 46530560);       // 20096x256
    __hip_bfloat16* wb2 = (__hip_bfloat16*)(ws + 56819712);       // 160000x64
    __hip_bfloat16* wb3 = (__hip_bfloat16*)(ws + 77299712);       // 67840x32
    float* rowsum = (float*)(ws + 81641472);                      // [4][512]
    float* adj    = (float*)(ws + 81649664);                      // [4][512]
    float* clog   = (float*)(ws + 81657856);                      // [3][512]

    conv_k<<<4096, 256, 0, stream>>>(hidden, cw,
        proj[0], proj[1], proj[2], proj[3], W[0], W[1], W[2], W[3],
        hb, pj, wb0, wb1, wb2, wb3, rowsum);

    // y_cat = hidden @ [proj0|proj1|proj2|proj3]^T  (single launch, K=1024)
    gemm_k<MODE_Y><<<dim3(11, 4), 256, 0, stream>>>(hb, 1024, 1024, pj,
        1408, 1408, nullptr, nullptr, nullptr, nullptr, 0, nullptr, y, 1408, 1408);

    // fused pass: raw logits -> out, rowsums, cluster-logit capture
    gemm_k<MODE_RW><<<dim3(157, 4), 256, 0, stream>>>(y, 1408, 1024, wb0,
        20003, 20000, bb[0], cb, rowsum, out, 20000, clog, nullptr, 0, 0);
    gemm_k<MODE_RW><<<dim3(157, 4), 256, 0, stream>>>(y + 1024, 1408, 256, wb1,
        20000, 20000, bb[1], bb[1], rowsum + 512, out + 20000, 20000, nullptr, nullptr, 0, 0);
    gemm_k<MODE_RW><<<dim3(1250, 4), 256, 0, stream>>>(y + 1280, 1408, 64, wb2,
        160000, 160000, bb[2], bb[2], rowsum + 1024, out + 40000, 160000, nullptr, nullptr, 0, 0);
    gemm_k<MODE_RW><<<dim3(530, 4), 256, 0, stream>>>(y + 1344, 1408, 32, wb3,
        67735, 67735, bb[3], bb[3], rowsum + 1536, out + 200000, 67735, nullptr, nullptr, 0, 0);

    finalize_k<<<1, 512, 0, stream>>>(rowsum, clog, adj);

    // out += adj[cluster][row]  (in-place, memory-bound)
    fixup_k<<<dim3(32, 512), 256, 0, stream>>>(out, adj);

    loss_k<<<1, 512, 0, stream>>>(out, target, out + (out_size - 1));
}